// Round 7
// baseline (208.294 us; speedup 1.0000x reference)
//
#include <hip/hip_runtime.h>

// Gather + ragged segment XOR reduction.
// History:
//  R1/R2: direct gather 142 us — L2-miss line-fill bound (table >> 4 MB/XCD L2).
//  R4: slice-bucket + XCD-pinned gather; gather ~60 us, bucket 67 us (occupancy).
//  R5: global-atomic bucketizer regressed (139 MB scattered writes). Reverted.
//  R6: LDS-staged ordered scatter + binary-search labels: bucket ~30 us,
//    gather 61 us == 42M L1 transactions (5 loads/token) at 1 req/cy/CU.
//  R7: padded 32B rows in ws -> int4+dword = 2 transactions/token (same 64B
//    line). Only kernel-B load path changed; LDS accumulation identical.

#define HPG        128     // hints per group
#define NSL        16      // slices (idx>>16), N <= 2^20
#define STAGE_CAP  12288   // tokens staged in LDS; mean 8192, +10 sigma

__device__ __forceinline__ int clip_idx(int v, int N) {
    return min(max(v, 0), N - 1);
}

// ---------------- pad kernel: entries [N,5] -> padded [N,8] ----------------
__global__ __launch_bounds__(256) void pad_entries(
    const int* __restrict__ e, int* __restrict__ p, int N)
{
    const int i = blockIdx.x * blockDim.x + threadIdx.x;
    if (i >= N) return;
    const int* s = e + (long)i * 5;
    int4 a = make_int4(s[0], s[1], s[2], s[3]);
    int4 b = make_int4(s[4], 0, 0, 0);
    int4* d = (int4*)(p + ((size_t)i << 3));
    d[0] = a;
    d[1] = b;
}

// ---------------- Kernel A: bucketize (one group per block) ----------------
__global__ __launch_bounds__(1024) void bucket_kernel(
    const int* __restrict__ blocks,
    const int* __restrict__ offsets,
    const int* __restrict__ starts,
    const int* __restrict__ bs_ptr,
    const int* __restrict__ entries,     // overflow path only
    int* __restrict__ out,               // overflow path only
    unsigned int* __restrict__ buck,     // [T] u32: idx(20) | localHint(<<20)
    unsigned int* __restrict__ tab,      // [NG*NSL*2] {absBase, count}
    int H, int N, int T)
{
    __shared__ unsigned int stage[STAGE_CAP];
    __shared__ int lstart[HPG + 1];
    __shared__ unsigned int cnt[NSL], off[NSL], lcur[NSL];

    const int g  = blockIdx.x;
    const int t  = threadIdx.x;
    const int h0 = g * HPG;
    const int h1 = min(H, h0 + HPG);
    const int nh = h1 - h0;
    const int bs = bs_ptr[0];

    if (t < nh) lstart[t] = starts[h0 + t];
    if (t == 0) lstart[nh] = (h1 < H) ? starts[h1] : T;
    if (t < NSL) { cnt[t] = 0; lcur[t] = 0; }
    __syncthreads();

    const int tokBase = lstart[0];
    const int count   = lstart[nh] - tokBase;
    const int staged  = min(count, STAGE_CAP);

    // pass 1: idx + hint (binary search) -> LDS stage; per-slice histogram
    for (int i = t; i < staged; i += 1024) {
        const int gpos = tokBase + i;
        const int idx  = clip_idx(blocks[gpos] * bs + offsets[gpos], N);
        int lo = 0, hi = nh - 1;                 // largest h: lstart[h] <= gpos
        while (lo < hi) {
            int m = (lo + hi + 1) >> 1;
            if (lstart[m] <= gpos) lo = m; else hi = m - 1;
        }
        stage[i] = (unsigned int)idx | ((unsigned int)lo << 20);
        atomicAdd(&cnt[(unsigned int)idx >> 16], 1u);
    }
    __syncthreads();

    // exclusive prefix over 16 slice counts
    if (t == 0) {
        unsigned int run = 0;
        for (int s = 0; s < NSL; ++s) { off[s] = run; run += cnt[s]; }
    }
    __syncthreads();

    if (t < NSL) {
        tab[(g * NSL + t) * 2 + 0] = (unsigned int)tokBase + off[t];
        tab[(g * NSL + t) * 2 + 1] = cnt[t];
    }

    // pass 2: ordered scatter into the group's own CSR range
    for (int i = t; i < staged; i += 1024) {
        const unsigned int w = stage[i];
        const unsigned int s = (w >> 16) & (NSL - 1);
        const unsigned int r = atomicAdd(&lcur[s], 1u);
        buck[(unsigned int)tokBase + off[s] + r] = w;
    }

    // overflow remainder (count > STAGE_CAP): statistically never; correctness.
    for (int i = staged + t; i < count; i += 1024) {
        const int gpos = tokBase + i;
        const int idx  = clip_idx(blocks[gpos] * bs + offsets[gpos], N);
        int lo = 0, hi = nh - 1;
        while (lo < hi) {
            int m = (lo + hi + 1) >> 1;
            if (lstart[m] <= gpos) lo = m; else hi = m - 1;
        }
        const int* row = entries + (long)idx * 5;
        int* o5 = out + (long)(h0 + lo) * 5;
        atomicXor(&o5[0], row[0]); atomicXor(&o5[1], row[1]);
        atomicXor(&o5[2], row[2]); atomicXor(&o5[3], row[3]);
        atomicXor(&o5[4], row[4]);
    }
}

// ---------------- Kernel B: XCD-pinned gather + LDS accumulate ----------------
// Grid = 2048 (resident capacity) so blockIdx&7 -> XCD round-robin holds.
// Block (x,g) touches only slices {x, x+8} -> L2-resident slice pair per XCD.
template<bool PAD>
__global__ __launch_bounds__(256) void gather_kernel(
    const unsigned int* __restrict__ buck,
    const unsigned int* __restrict__ tab,
    const int* __restrict__ table,     // PAD ? padded[N,8] : entries[N,5]
    int* __restrict__ out,
    int H, int NG, int nSl, int groupsPerBlock)
{
    __shared__ int acc[HPG * 5];

    const int B = blockIdx.x;
    const int x = B & 7;
    const int g0 = B >> 3;
    const int t = threadIdx.x;
    const int gStride = gridDim.x >> 3;

    for (int k = 0; k < groupsPerBlock; ++k) {
        const int g = g0 + k * gStride;
        if (g >= NG) break;

        for (int i = t; i < HPG * 5; i += 256) acc[i] = 0;
        __syncthreads();

        for (int s = x; s < nSl; s += 8) {
            const unsigned int base = tab[(g * NSL + s) * 2 + 0];
            const unsigned int cn   = tab[(g * NSL + s) * 2 + 1];
            for (unsigned int i = t; i < cn; i += 256) {
                const unsigned int w = buck[base + i];
                const int idx = (int)(w & 0xFFFFFu);
                const int h   = (int)(w >> 20);
                int e0, e1, e2, e3, e4;
                if (PAD) {
                    const int* row = table + ((size_t)idx << 3);
                    int4 v = *(const int4*)row;    // cols 0-3, 16B aligned
                    e4 = row[4];                   // col 4, same 64B line
                    e0 = v.x; e1 = v.y; e2 = v.z; e3 = v.w;
                } else {
                    const int* row = table + (long)idx * 5;
                    e0 = row[0]; e1 = row[1]; e2 = row[2];
                    e3 = row[3]; e4 = row[4];
                }
                atomicXor(&acc[h * 5 + 0], e0);
                atomicXor(&acc[h * 5 + 1], e1);
                atomicXor(&acc[h * 5 + 2], e2);
                atomicXor(&acc[h * 5 + 3], e3);
                atomicXor(&acc[h * 5 + 4], e4);
            }
        }
        __syncthreads();

        const long obase = (long)g * HPG * 5;
        const long omax  = (long)H * 5;
        for (int i = t; i < HPG * 5; i += 256) {
            const long o = obase + i;
            if (o < omax) {
                const int v = acc[i];
                if (v) atomicXor(&out[o], v);
            }
        }
        __syncthreads();
    }
}

// ---------------- Fallback (R1): direct gather, wave per hint ----------------
__global__ __launch_bounds__(256) void hint_xor_wave(
    const int* __restrict__ entries,
    const int* __restrict__ blocks,
    const int* __restrict__ offsets,
    const int* __restrict__ starts,
    const int* __restrict__ sizes,
    const int* __restrict__ bs_ptr,
    int* __restrict__ out,
    int H, int N)
{
    const int gtid = blockIdx.x * blockDim.x + threadIdx.x;
    const int hint = gtid >> 6;
    const int lane = gtid & 63;
    if (hint >= H) return;

    const int start = starts[hint];
    const int size  = sizes[hint];
    const int bs    = bs_ptr[0];

    int a0 = 0, a1 = 0, a2 = 0, a3 = 0, a4 = 0;
    for (int j = lane; j < size; j += 64) {
        int idx = clip_idx(blocks[start + j] * bs + offsets[start + j], N);
        const int* row = entries + (size_t)idx * 5;
        a0 ^= row[0]; a1 ^= row[1]; a2 ^= row[2]; a3 ^= row[3]; a4 ^= row[4];
    }
    #pragma unroll
    for (int m = 1; m < 64; m <<= 1) {
        a0 ^= __shfl_xor(a0, m);
        a1 ^= __shfl_xor(a1, m);
        a2 ^= __shfl_xor(a2, m);
        a3 ^= __shfl_xor(a3, m);
        a4 ^= __shfl_xor(a4, m);
    }
    if (lane == 0) {
        int* o = out + (size_t)hint * 5;
        o[0] = a0; o[1] = a1; o[2] = a2; o[3] = a3; o[4] = a4;
    }
}

extern "C" void kernel_launch(void* const* d_in, const int* in_sizes, int n_in,
                              void* d_out, int out_size, void* d_ws, size_t ws_size,
                              hipStream_t stream) {
    const int* entries = (const int*)d_in[0];
    const int* blocks  = (const int*)d_in[1];
    const int* offsets = (const int*)d_in[2];
    const int* starts  = (const int*)d_in[3];
    const int* sizes   = (const int*)d_in[4];
    const int* bs      = (const int*)d_in[5];
    int* out = (int*)d_out;

    const int H = in_sizes[3];
    const int T = in_sizes[1];
    const int N = in_sizes[0] / 5;

    const int NG  = (H + HPG - 1) / HPG;
    const int nSl = (N + 65535) >> 16;

    // ws layout: buck [T] u32 | tab [NG*NSL*2] u32 | padded [N*8] int
    const size_t buckOff   = 0;
    const size_t buckBytes = (size_t)T * 4;
    const size_t tabOff    = (buckOff + buckBytes + 63) & ~(size_t)63;
    const size_t tabBytes  = (size_t)NG * NSL * 2 * 4;
    const size_t padOff    = (tabOff + tabBytes + 63) & ~(size_t)63;
    const size_t padBytes  = (size_t)N * 8 * sizeof(int);
    const size_t needBase  = padOff;                 // through tab
    const size_t needPad   = padOff + padBytes + 64;

    const bool okBase = (N <= (1 << 20)) && (nSl <= NSL) &&
                        (ws_size >= needBase) && (H <= (1 << 27));
    const bool okPad  = okBase && (ws_size >= needPad);

    if (okBase) {
        unsigned int* buck = (unsigned int*)((char*)d_ws + buckOff);
        unsigned int* tab  = (unsigned int*)((char*)d_ws + tabOff);
        int*          pad  = (int*)((char*)d_ws + padOff);

        hipMemsetAsync(d_out, 0, (size_t)out_size * sizeof(int), stream);

        if (okPad) {
            const int pgrid = (N + 255) / 256;
            hipLaunchKernelGGL(pad_entries, dim3(pgrid), dim3(256), 0, stream,
                               entries, pad, N);
        }

        hipLaunchKernelGGL(bucket_kernel, dim3(NG), dim3(1024), 0, stream,
                           blocks, offsets, starts, bs, entries, out,
                           buck, tab, H, N, T);

        int gridB = 2048;
        if (gridB > NG * 8) gridB = NG * 8;
        const int gStride = (gridB >= 8) ? (gridB >> 3) : 1;
        const int gpb = (NG + gStride - 1) / gStride;

        if (okPad) {
            hipLaunchKernelGGL((gather_kernel<true>), dim3(gridB), dim3(256), 0,
                               stream, buck, tab, pad, out, H, NG, nSl, gpb);
        } else {
            hipLaunchKernelGGL((gather_kernel<false>), dim3(gridB), dim3(256), 0,
                               stream, buck, tab, entries, out, H, NG, nSl, gpb);
        }
    } else {
        const long total_threads = (long)H * 64;
        const int block = 256;
        const int grid = (int)((total_threads + block - 1) / block);
        hipLaunchKernelGGL(hint_xor_wave, dim3(grid), dim3(block), 0, stream,
                           entries, blocks, offsets, starts, sizes, bs, out, H, N);
    }
}